// Round 1
// baseline (387.431 us; speedup 1.0000x reference)
//
#include <hip/hip_runtime.h>

typedef unsigned short u16;
typedef __bf16 bf16x8 __attribute__((ext_vector_type(8)));
typedef float f32x4 __attribute__((ext_vector_type(4)));

// ---------- sizes ----------
#define Bsz 8192
#define Fdim 1024
#define Udim 512
#define Odim 3
#define Adim 6
#define Hdim 4

// ws element offsets (u16 elements)
#define OFF_FEAT   0
#define OFF_WAL    8388608
#define OFF_WIN    8912896
#define OFF_WOUT   9699328
#define OFF_WAH    9961472
#define OFF_WOL    10485760
#define OFF_WOH    12058624
#define OFF_CAT    12845056
#define OFF_OPP    21233664
#define OFF_Q      33816576
#define OFF_KV     38010880
#define OFF_ATT    63176704
#define OFF_AGH    67371008
#define OFF_OPH    71565312

// d_out offsets (fp32 elements)
#define OUT_AP 0
#define OUT_AV 49152
#define OUT_OP 57344
#define OUT_OV 204800
#define OUT_IN 229376

__device__ __forceinline__ u16 f2bf(float f) {
  return __builtin_bit_cast(u16, (__bf16)f);
}
__device__ __forceinline__ float bf2f(u16 u) {
  return (float)__builtin_bit_cast(__bf16, u);
}

__device__ __forceinline__ void gload16(const u16* g, u16* s) {
  __builtin_amdgcn_global_load_lds(
      (const __attribute__((address_space(1))) unsigned int*)g,
      (__attribute__((address_space(3))) unsigned int*)s, 16, 0, 0);
}

// ---------- fp32 -> bf16 conversion of features + all GEMM weights ----------
// segments (float4 units): feat, W_al, W_in, W_out, W_ah, W_ol, W_oh
#define CV_E0 2097152
#define CV_E1 2228224
#define CV_E2 2424832
#define CV_E3 2490368
#define CV_E4 2621440
#define CV_E5 3014656
#define CV_E6 3211264
__global__ __launch_bounds__(256) void convert_all(
    const float* __restrict__ f, const float* __restrict__ wal,
    const float* __restrict__ win, const float* __restrict__ wout,
    const float* __restrict__ wah, const float* __restrict__ wol,
    const float* __restrict__ woh, u16* __restrict__ dst) {
  int i = blockIdx.x * 256 + threadIdx.x;
  if (i >= CV_E6) return;
  const float* src;
  int base;
  if (i < CV_E0)      { src = f;    base = 0; }
  else if (i < CV_E1) { src = wal;  base = CV_E0; }
  else if (i < CV_E2) { src = win;  base = CV_E1; }
  else if (i < CV_E3) { src = wout; base = CV_E2; }
  else if (i < CV_E4) { src = wah;  base = CV_E3; }
  else if (i < CV_E5) { src = wol;  base = CV_E4; }
  else                { src = woh;  base = CV_E5; }
  float4 v = ((const float4*)src)[i - base];
  ushort4 o;
  o.x = f2bf(v.x); o.y = f2bf(v.y); o.z = f2bf(v.z); o.w = f2bf(v.w);
  ((ushort4*)dst)[i] = o;
}

// ---------- bf16 GEMM: C[m,n] = act((sum_k A[m,k]*Bw[n,k] + bias[n]) * scale) ----------
// BM=128 fixed, BN in {64,128}. 256 threads = 4 waves in 2x2; wave tile 64 x BN/2.
template <int BN, bool ELU>
__global__ __launch_bounds__(256) void gemm_bt(
    const u16* __restrict__ A, const u16* __restrict__ Bw, u16* __restrict__ C,
    const float* __restrict__ bias, int K, int lda, int ldb, int ldc,
    long sAz, long sBz, long sCz, int sbz, float scale) {
  constexpr int BM = 128, BK = 32;
  constexpr int NI = BN / 32;
  __shared__ __align__(16) u16 As[BM * BK];
  __shared__ __align__(16) u16 Bs[BN * BK];
  const int wave = threadIdx.x >> 6, lane = threadIdx.x & 63;
  const int z = blockIdx.z;
  A += (size_t)z * sAz;
  Bw += (size_t)z * sBz;
  C += (size_t)z * sCz;
  bias += (size_t)z * sbz;
  const int tM = blockIdx.y * BM, tN = blockIdx.x * BN;
  const int wr = wave >> 1, wc = wave & 1;

  f32x4 acc[4][NI];
#pragma unroll
  for (int i = 0; i < 4; i++)
#pragma unroll
    for (int j = 0; j < NI; j++) acc[i][j] = (f32x4){0.f, 0.f, 0.f, 0.f};

  const int srow = lane >> 2;        // 0..15 row within 16-row group
  const int scol = (lane & 3) * 8;   // 0,8,16,24 k-element offset

  for (int k0 = 0; k0 < K; k0 += BK) {
    __syncthreads();
    // stage A tile: 128 rows x 32 k, 8 lds-instrs, 2 per wave
#pragma unroll
    for (int i = 0; i < 2; ++i) {
      int r = wave * 32 + i * 16;
      gload16(A + (size_t)(tM + r + srow) * lda + k0 + scol, &As[r * BK]);
    }
    // stage B tile: BN rows x 32 k
#pragma unroll
    for (int i = 0; i < BN / 64; ++i) {
      int r = (wave * (BN / 64) + i) * 16;
      gload16(Bw + (size_t)(tN + r + srow) * ldb + k0 + scol, &Bs[r * BK]);
    }
    __syncthreads();
    bf16x8 af[4], bfr[NI];
#pragma unroll
    for (int mi = 0; mi < 4; mi++)
      af[mi] = *(const bf16x8*)&As[(wr * 64 + mi * 16 + (lane & 15)) * BK + (lane >> 4) * 8];
#pragma unroll
    for (int ni = 0; ni < NI; ni++)
      bfr[ni] = *(const bf16x8*)&Bs[(wc * (BN / 2) + ni * 16 + (lane & 15)) * BK + (lane >> 4) * 8];
#pragma unroll
    for (int mi = 0; mi < 4; mi++)
#pragma unroll
      for (int ni = 0; ni < NI; ni++)
        acc[mi][ni] = __builtin_amdgcn_mfma_f32_16x16x32_bf16(af[mi], bfr[ni], acc[mi][ni], 0, 0, 0);
  }

  // epilogue: C/D layout col=lane&15, row=(lane>>4)*4+reg
#pragma unroll
  for (int ni = 0; ni < NI; ni++) {
    int col = tN + wc * (BN / 2) + ni * 16 + (lane & 15);
    float bv = bias[col];
#pragma unroll
    for (int mi = 0; mi < 4; mi++) {
      int row0 = tM + wr * 64 + mi * 16 + (lane >> 4) * 4;
#pragma unroll
      for (int r = 0; r < 4; r++) {
        float v = (acc[mi][ni][r] + bv) * scale;
        if (ELU) v = v > 0.f ? v : (__expf(v) - 1.f);
        C[(size_t)(row0 + r) * ldc + col] = f2bf(v);
      }
    }
  }
}

// ---------- attention: scores/softmax over O=3, attn out + influences ----------
// one wave per batch row; lane covers 2 of 128 head dims
__global__ __launch_bounds__(256) void attn_kernel(
    const u16* __restrict__ q, const u16* __restrict__ kv,
    u16* __restrict__ attn, float* __restrict__ influ) {
  const int wave = threadIdx.x >> 6, lane = threadIdx.x & 63;
  const int b = blockIdx.x * 4 + wave;
  const size_t qb = (size_t)b * 512;
  float wacc0 = 0.f, wacc1 = 0.f, wacc2 = 0.f;
#pragma unroll
  for (int h = 0; h < 4; ++h) {
    const int off = h * 128 + lane * 2;
    ushort2 qu = *(const ushort2*)(q + qb + off);
    float qx = bf2f(qu.x), qy = bf2f(qu.y);
    float s[3];
#pragma unroll
    for (int o = 0; o < 3; ++o) {
      ushort2 ku = *(const ushort2*)(kv + (size_t)o * (Bsz * 1024) + (size_t)b * 1024 + off);
      float p = qx * bf2f(ku.x) + qy * bf2f(ku.y);
#pragma unroll
      for (int d = 32; d; d >>= 1) p += __shfl_xor(p, d, 64);
      s[o] = p;
    }
    float m = fmaxf(s[0], fmaxf(s[1], s[2]));
    float e0 = __expf(s[0] - m), e1 = __expf(s[1] - m), e2 = __expf(s[2] - m);
    float inv = 1.f / (e0 + e1 + e2);
    float w0 = e0 * inv, w1 = e1 * inv, w2 = e2 * inv;
    wacc0 += w0; wacc1 += w1; wacc2 += w2;
    float ax = 0.f, ay = 0.f;
#pragma unroll
    for (int o = 0; o < 3; ++o) {
      float w = (o == 0) ? w0 : (o == 1) ? w1 : w2;
      ushort2 vu = *(const ushort2*)(kv + (size_t)o * (Bsz * 1024) + (size_t)b * 1024 + 512 + off);
      ax += w * bf2f(vu.x);
      ay += w * bf2f(vu.y);
    }
    ushort2 st; st.x = f2bf(ax); st.y = f2bf(ay);
    *(ushort2*)(attn + qb + off) = st;
  }
  if (lane == 0) {
    influ[b * 3 + 0] = wacc0 * 0.25f;
    influ[b * 3 + 1] = wacc1 * 0.25f;
    influ[b * 3 + 2] = wacc2 * 0.25f;
  }
}

// ---------- final heads: 28 length-512 dots per row ----------
__device__ __forceinline__ float wred(float v) {
#pragma unroll
  for (int d = 32; d; d >>= 1) v += __shfl_xor(v, d, 64);
  return v;
}

__global__ __launch_bounds__(256) void heads_kernel(
    const u16* __restrict__ ah, const u16* __restrict__ oh,
    const float* __restrict__ Wap, const float* __restrict__ bap,
    const float* __restrict__ Wav, const float* __restrict__ bav,
    const float* __restrict__ Wop, const float* __restrict__ bop,
    const float* __restrict__ Wov, const float* __restrict__ bov,
    float* __restrict__ out) {
  __shared__ float sW[14336];  // Wap 3072 | Wav 512 | Wop 9216 | Wov 1536
  for (int i = threadIdx.x; i < 14336; i += 256) {
    float v;
    if (i < 3072)       v = Wap[i];
    else if (i < 3584)  v = Wav[i - 3072];
    else if (i < 12800) v = Wop[i - 3584];
    else                v = Wov[i - 12800];
    sW[i] = v;
  }
  __syncthreads();
  const int wave = threadIdx.x >> 6, lane = threadIdx.x & 63;
  for (int it = 0; it < 8; ++it) {
    const int b = blockIdx.x * 32 + wave * 8 + it;
    float a[8], ov[3][8];
#pragma unroll
    for (int j = 0; j < 8; j++) {
      a[j] = bf2f(ah[(size_t)b * 512 + j * 64 + lane]);
#pragma unroll
      for (int o = 0; o < 3; o++)
        ov[o][j] = bf2f(oh[(size_t)o * (Bsz * 512) + (size_t)b * 512 + j * 64 + lane]);
    }
#pragma unroll
    for (int p = 0; p < 6; p++) {
      float s = 0.f;
#pragma unroll
      for (int j = 0; j < 8; j++) s += a[j] * sW[p * 512 + j * 64 + lane];
      s = wred(s);
      if (lane == 0) out[OUT_AP + b * 6 + p] = s + bap[p];
    }
    {
      float s = 0.f;
#pragma unroll
      for (int j = 0; j < 8; j++) s += a[j] * sW[3072 + j * 64 + lane];
      s = wred(s);
      if (lane == 0) out[OUT_AV + b] = s + bav[0];
    }
#pragma unroll
    for (int o = 0; o < 3; o++) {
#pragma unroll
      for (int p = 0; p < 6; p++) {
        float s = 0.f;
#pragma unroll
        for (int j = 0; j < 8; j++) s += ov[o][j] * sW[3584 + (o * 6 + p) * 512 + j * 64 + lane];
        s = wred(s);
        if (lane == 0) out[OUT_OP + b * 18 + o * 6 + p] = s + bop[o * 6 + p];
      }
      float s = 0.f;
#pragma unroll
      for (int j = 0; j < 8; j++) s += ov[o][j] * sW[12800 + o * 512 + j * 64 + lane];
      s = wred(s);
      if (lane == 0) out[OUT_OV + b * 3 + o] = s + bov[o];
    }
  }
}

extern "C" void kernel_launch(void* const* d_in, const int* in_sizes, int n_in,
                              void* d_out, int out_size, void* d_ws, size_t ws_size,
                              hipStream_t stream) {
  (void)in_sizes; (void)n_in; (void)out_size; (void)ws_size;
  const float* f     = (const float*)d_in[0];
  const float* W_al  = (const float*)d_in[1];
  const float* b_al  = (const float*)d_in[2];
  const float* W_in  = (const float*)d_in[3];
  const float* b_in  = (const float*)d_in[4];
  const float* W_out = (const float*)d_in[5];
  const float* b_out = (const float*)d_in[6];
  const float* W_ah  = (const float*)d_in[7];
  const float* b_ah  = (const float*)d_in[8];
  const float* W_ap  = (const float*)d_in[9];
  const float* b_ap  = (const float*)d_in[10];
  const float* W_av  = (const float*)d_in[11];
  const float* b_av  = (const float*)d_in[12];
  const float* W_ol  = (const float*)d_in[13];
  const float* b_ol  = (const float*)d_in[14];
  const float* W_oh  = (const float*)d_in[15];
  const float* b_oh  = (const float*)d_in[16];
  const float* W_op  = (const float*)d_in[17];
  const float* b_op  = (const float*)d_in[18];
  const float* W_ov  = (const float*)d_in[19];
  const float* b_ov  = (const float*)d_in[20];
  float* out = (float*)d_out;
  u16* ws = (u16*)d_ws;

  u16* feat = ws + OFF_FEAT;
  u16* wal  = ws + OFF_WAL;
  u16* win  = ws + OFF_WIN;
  u16* wout = ws + OFF_WOUT;
  u16* wah  = ws + OFF_WAH;
  u16* wol  = ws + OFF_WOL;
  u16* woh  = ws + OFF_WOH;
  u16* cat  = ws + OFF_CAT;   // B x 1024 : [agent_latent | attn_out]
  u16* opp  = ws + OFF_OPP;   // B x 1536 : opp_lat, col block o
  u16* qb   = ws + OFF_Q;     // B x 512
  u16* kvb  = ws + OFF_KV;    // 3 x B x 1024 : [k | v]
  u16* att  = ws + OFF_ATT;   // B x 512
  u16* agh  = ws + OFF_AGH;   // B x 512
  u16* oph  = ws + OFF_OPH;   // 3 x B x 512

  convert_all<<<12544, 256, 0, stream>>>(f, W_al, W_in, W_out, W_ah, W_ol, W_oh, ws);

  // agent_latent = elu(feat @ W_al^T + b_al) -> cat[:, :512]
  gemm_bt<64, true><<<dim3(8, 64, 1), 256, 0, stream>>>(
      feat, wal, cat, b_al, 1024, 1024, 1024, 1024, 0, 0, 0, 0, 1.f);
  // opp_lat = elu(feat @ W_ol_stacked^T + b_ol) -> opp (B x 1536)
  gemm_bt<128, true><<<dim3(12, 64, 1), 256, 0, stream>>>(
      feat, wol, opp, b_ol, 1024, 1024, 1024, 1536, 0, 0, 0, 0, 1.f);
  // q = (agent_latent @ Wq^T + bq) / sqrt(128)
  gemm_bt<64, false><<<dim3(8, 64, 1), 256, 0, stream>>>(
      cat, win, qb, b_in, 512, 1024, 512, 512, 0, 0, 0, 0, 0.08838834764831845f);
  // kv[o] = opp_lat[o] @ [Wk;Wv]^T + [bk;bv]   (z = o)
  gemm_bt<128, false><<<dim3(8, 64, 3), 256, 0, stream>>>(
      opp, win + 262144, kvb, b_in + 512, 512, 1536, 512, 1024, 512, 0, 8388608, 0, 1.f);

  attn_kernel<<<2048, 256, 0, stream>>>(qb, kvb, att, out + OUT_IN);

  // attn_out = attn @ W_out^T + b_out -> cat[:, 512:]
  gemm_bt<64, false><<<dim3(8, 64, 1), 256, 0, stream>>>(
      att, wout, cat + 512, b_out, 512, 512, 512, 1024, 0, 0, 0, 0, 1.f);
  // agent_head = elu(cat @ W_ah^T + b_ah)
  gemm_bt<64, true><<<dim3(8, 64, 1), 256, 0, stream>>>(
      cat, wah, agh, b_ah, 1024, 1024, 1024, 512, 0, 0, 0, 0, 1.f);
  // opp_heads[o] = elu(opp_lat[o] @ W_oh[o]^T + b_oh[o])
  gemm_bt<128, true><<<dim3(4, 64, 3), 256, 0, stream>>>(
      opp, woh, oph, b_oh, 512, 1536, 512, 512, 512, 262144, 4194304, 512, 1.f);

  heads_kernel<<<256, 256, 0, stream>>>(agh, oph, W_ap, b_ap, W_av, b_av,
                                        W_op, b_op, W_ov, b_ov, out);
}

// Round 2
// 354.723 us; speedup vs baseline: 1.0922x; 1.0922x over previous
//
#include <hip/hip_runtime.h>

typedef unsigned short u16;
typedef __bf16 bf16x8 __attribute__((ext_vector_type(8)));
typedef float f32x4 __attribute__((ext_vector_type(4)));

// ---------- sizes ----------
#define Bsz 8192
#define Fdim 1024
#define Udim 512
#define Odim 3
#define Adim 6
#define Hdim 4

// ws element offsets (u16 elements)
#define OFF_FEAT   0
#define OFF_WAL    8388608
#define OFF_WIN    8912896
#define OFF_WOUT   9699328
#define OFF_WAH    9961472
#define OFF_WOL    10485760
#define OFF_WOH    12058624
#define OFF_CAT    12845056
#define OFF_OPP    21233664
#define OFF_Q      33816576
#define OFF_KV     38010880
#define OFF_ATT    63176704
#define OFF_AGH    67371008
#define OFF_OPH    71565312

// d_out offsets (fp32 elements)
#define OUT_AP 0
#define OUT_AV 49152
#define OUT_OP 57344
#define OUT_OV 204800
#define OUT_IN 229376

__device__ __forceinline__ u16 f2bf(float f) {
  return __builtin_bit_cast(u16, (__bf16)f);
}
__device__ __forceinline__ float bf2f(u16 u) {
  return (float)__builtin_bit_cast(__bf16, u);
}

__device__ __forceinline__ void gload16(const u16* g, u16* s) {
  __builtin_amdgcn_global_load_lds(
      (const __attribute__((address_space(1))) unsigned int*)g,
      (__attribute__((address_space(3))) unsigned int*)s, 16, 0, 0);
}

// ---------- fp32 -> bf16 conversion of features + all GEMM weights ----------
// segments (float4 units): feat, W_al, W_in, W_out, W_ah, W_ol, W_oh
#define CV_E0 2097152
#define CV_E1 2228224
#define CV_E2 2424832
#define CV_E3 2490368
#define CV_E4 2621440
#define CV_E5 3014656
#define CV_E6 3211264
__global__ __launch_bounds__(256) void convert_all(
    const float* __restrict__ f, const float* __restrict__ wal,
    const float* __restrict__ win, const float* __restrict__ wout,
    const float* __restrict__ wah, const float* __restrict__ wol,
    const float* __restrict__ woh, u16* __restrict__ dst) {
  int i = blockIdx.x * 256 + threadIdx.x;
  if (i >= CV_E6) return;
  const float* src;
  int base;
  if (i < CV_E0)      { src = f;    base = 0; }
  else if (i < CV_E1) { src = wal;  base = CV_E0; }
  else if (i < CV_E2) { src = win;  base = CV_E1; }
  else if (i < CV_E3) { src = wout; base = CV_E2; }
  else if (i < CV_E4) { src = wah;  base = CV_E3; }
  else if (i < CV_E5) { src = wol;  base = CV_E4; }
  else                { src = woh;  base = CV_E5; }
  float4 v = ((const float4*)src)[i - base];
  ushort4 o;
  o.x = f2bf(v.x); o.y = f2bf(v.y); o.z = f2bf(v.z); o.w = f2bf(v.w);
  ((ushort4*)dst)[i] = o;
}

// ---------- bf16 GEMM: C[m,n] = act((sum_k A[m,k]*Bw[n,k] + bias[n]) * scale) ----------
// BM=128 fixed, BN in {64,128}. 256 threads = 4 waves in 2x2; wave tile 64 x BN/2.
template <int BN, bool ELU>
__global__ __launch_bounds__(256) void gemm_bt(
    const u16* __restrict__ A, const u16* __restrict__ Bw, u16* __restrict__ C,
    const float* __restrict__ bias, int K, int lda, int ldb, int ldc,
    long sAz, long sBz, long sCz, int sbz, float scale) {
  constexpr int BM = 128, BK = 32;
  constexpr int NI = BN / 32;
  __shared__ __align__(16) u16 As[BM * BK];
  __shared__ __align__(16) u16 Bs[BN * BK];
  const int wave = threadIdx.x >> 6, lane = threadIdx.x & 63;
  const int z = blockIdx.z;
  A += (size_t)z * sAz;
  Bw += (size_t)z * sBz;
  C += (size_t)z * sCz;
  bias += (size_t)z * sbz;
  const int tM = blockIdx.y * BM, tN = blockIdx.x * BN;
  const int wr = wave >> 1, wc = wave & 1;

  f32x4 acc[4][NI];
#pragma unroll
  for (int i = 0; i < 4; i++)
#pragma unroll
    for (int j = 0; j < NI; j++) acc[i][j] = (f32x4){0.f, 0.f, 0.f, 0.f};

  const int srow = lane >> 2;        // 0..15 row within 16-row group
  const int scol = (lane & 3) * 8;   // 0,8,16,24 k-element offset

  for (int k0 = 0; k0 < K; k0 += BK) {
    __syncthreads();
    // stage A tile: 128 rows x 32 k, 8 lds-instrs, 2 per wave
#pragma unroll
    for (int i = 0; i < 2; ++i) {
      int r = wave * 32 + i * 16;
      gload16(A + (size_t)(tM + r + srow) * lda + k0 + scol, &As[r * BK]);
    }
    // stage B tile: BN rows x 32 k
#pragma unroll
    for (int i = 0; i < BN / 64; ++i) {
      int r = (wave * (BN / 64) + i) * 16;
      gload16(Bw + (size_t)(tN + r + srow) * ldb + k0 + scol, &Bs[r * BK]);
    }
    __syncthreads();
    bf16x8 af[4], bfr[NI];
#pragma unroll
    for (int mi = 0; mi < 4; mi++)
      af[mi] = *(const bf16x8*)&As[(wr * 64 + mi * 16 + (lane & 15)) * BK + (lane >> 4) * 8];
#pragma unroll
    for (int ni = 0; ni < NI; ni++)
      bfr[ni] = *(const bf16x8*)&Bs[(wc * (BN / 2) + ni * 16 + (lane & 15)) * BK + (lane >> 4) * 8];
#pragma unroll
    for (int mi = 0; mi < 4; mi++)
#pragma unroll
      for (int ni = 0; ni < NI; ni++)
        acc[mi][ni] = __builtin_amdgcn_mfma_f32_16x16x32_bf16(af[mi], bfr[ni], acc[mi][ni], 0, 0, 0);
  }

  // epilogue: C/D layout col=lane&15, row=(lane>>4)*4+reg
#pragma unroll
  for (int ni = 0; ni < NI; ni++) {
    int col = tN + wc * (BN / 2) + ni * 16 + (lane & 15);
    float bv = bias[col];
#pragma unroll
    for (int mi = 0; mi < 4; mi++) {
      int row0 = tM + wr * 64 + mi * 16 + (lane >> 4) * 4;
#pragma unroll
      for (int r = 0; r < 4; r++) {
        float v = (acc[mi][ni][r] + bv) * scale;
        if (ELU) v = v > 0.f ? v : (__expf(v) - 1.f);
        C[(size_t)(row0 + r) * ldc + col] = f2bf(v);
      }
    }
  }
}

// ---------- attention: scores/softmax over O=3, attn out + influences ----------
// one wave per batch row; lane covers 2 of 128 head dims
__global__ __launch_bounds__(256) void attn_kernel(
    const u16* __restrict__ q, const u16* __restrict__ kv,
    u16* __restrict__ attn, float* __restrict__ influ) {
  const int wave = threadIdx.x >> 6, lane = threadIdx.x & 63;
  const int b = blockIdx.x * 4 + wave;
  const size_t qb = (size_t)b * 512;
  float wacc0 = 0.f, wacc1 = 0.f, wacc2 = 0.f;
#pragma unroll
  for (int h = 0; h < 4; ++h) {
    const int off = h * 128 + lane * 2;
    ushort2 qu = *(const ushort2*)(q + qb + off);
    float qx = bf2f(qu.x), qy = bf2f(qu.y);
    float s[3];
#pragma unroll
    for (int o = 0; o < 3; ++o) {
      ushort2 ku = *(const ushort2*)(kv + (size_t)o * (Bsz * 1024) + (size_t)b * 1024 + off);
      float p = qx * bf2f(ku.x) + qy * bf2f(ku.y);
#pragma unroll
      for (int d = 32; d; d >>= 1) p += __shfl_xor(p, d, 64);
      s[o] = p;
    }
    float m = fmaxf(s[0], fmaxf(s[1], s[2]));
    float e0 = __expf(s[0] - m), e1 = __expf(s[1] - m), e2 = __expf(s[2] - m);
    float inv = 1.f / (e0 + e1 + e2);
    float w0 = e0 * inv, w1 = e1 * inv, w2 = e2 * inv;
    wacc0 += w0; wacc1 += w1; wacc2 += w2;
    float ax = 0.f, ay = 0.f;
#pragma unroll
    for (int o = 0; o < 3; ++o) {
      float w = (o == 0) ? w0 : (o == 1) ? w1 : w2;
      ushort2 vu = *(const ushort2*)(kv + (size_t)o * (Bsz * 1024) + (size_t)b * 1024 + 512 + off);
      ax += w * bf2f(vu.x);
      ay += w * bf2f(vu.y);
    }
    ushort2 st; st.x = f2bf(ax); st.y = f2bf(ay);
    *(ushort2*)(attn + qb + off) = st;
  }
  if (lane == 0) {
    influ[b * 3 + 0] = wacc0 * 0.25f;
    influ[b * 3 + 1] = wacc1 * 0.25f;
    influ[b * 3 + 2] = wacc2 * 0.25f;
  }
}

// ---------- final heads: 28 length-512 dots per row ----------
// lane mapping: kq = lane&7 owns a 64-elem K slice, r = lane>>3 owns a row.
// 8 rows per wave, 32 per block, grid 256 = 8192 rows.
// Reduction is only across the 8 kq lanes: 3 shuffles (xor 1,2,4).
__global__ __launch_bounds__(256) void heads_kernel(
    const u16* __restrict__ ah, const u16* __restrict__ oh,
    const float* __restrict__ Wap, const float* __restrict__ bap,
    const float* __restrict__ Wav, const float* __restrict__ bav,
    const float* __restrict__ Wop, const float* __restrict__ bop,
    const float* __restrict__ Wov, const float* __restrict__ bov,
    float* __restrict__ out) {
  // sW layout: segment s (0=agent,1..3=opp o) at s*3584; p*512 for p=0..5
  // policy rows, 3072..3583 value row.
  __shared__ float sW[14336];
  for (int i = threadIdx.x; i < 14336; i += 256) {
    int s = i / 3584, rem = i - s * 3584;
    float v;
    if (s == 0) {
      v = (rem < 3072) ? Wap[rem] : Wav[rem - 3072];
    } else {
      int o = s - 1;
      v = (rem < 3072) ? Wop[o * 3072 + rem] : Wov[o * 512 + (rem - 3072)];
    }
    sW[i] = v;
  }
  __syncthreads();
  const int wave = threadIdx.x >> 6, lane = threadIdx.x & 63;
  const int kq = lane & 7, r = lane >> 3;
  const int b = blockIdx.x * 32 + wave * 8 + r;

  // load all 4 segments' A chunks up front (16B per load, 8 consecutive
  // lanes cover a contiguous 128B)
  const u16* srcs[4] = {ah + (size_t)b * 512,
                        oh + (size_t)b * 512,
                        oh + (size_t)(Bsz + b) * 512,
                        oh + (size_t)(2 * Bsz + b) * 512};
  bf16x8 a[4][8];
#pragma unroll
  for (int s = 0; s < 4; s++)
#pragma unroll
    for (int c = 0; c < 8; c++)
      a[s][c] = *(const bf16x8*)(srcs[s] + c * 64 + kq * 8);

#pragma unroll
  for (int s = 0; s < 4; s++) {
#pragma unroll
    for (int p = 0; p < 7; p++) {
      const float* w = &sW[s * 3584 + p * 512 + kq * 8];
      float acc = 0.f;
#pragma unroll
      for (int c = 0; c < 8; c++) {
#pragma unroll
        for (int j = 0; j < 8; j++)
          acc += (float)a[s][c][j] * w[c * 64 + j];
      }
      acc += __shfl_xor(acc, 1, 64);
      acc += __shfl_xor(acc, 2, 64);
      acc += __shfl_xor(acc, 4, 64);
      if (kq == p) {
        if (s == 0) {
          if (p < 6) out[OUT_AP + b * 6 + p] = acc + bap[p];
          else       out[OUT_AV + b] = acc + bav[0];
        } else {
          int o = s - 1;
          if (p < 6) out[OUT_OP + b * 18 + o * 6 + p] = acc + bop[o * 6 + p];
          else       out[OUT_OV + b * 3 + o] = acc + bov[o];
        }
      }
    }
  }
}

extern "C" void kernel_launch(void* const* d_in, const int* in_sizes, int n_in,
                              void* d_out, int out_size, void* d_ws, size_t ws_size,
                              hipStream_t stream) {
  (void)in_sizes; (void)n_in; (void)out_size; (void)ws_size;
  const float* f     = (const float*)d_in[0];
  const float* W_al  = (const float*)d_in[1];
  const float* b_al  = (const float*)d_in[2];
  const float* W_in  = (const float*)d_in[3];
  const float* b_in  = (const float*)d_in[4];
  const float* W_out = (const float*)d_in[5];
  const float* b_out = (const float*)d_in[6];
  const float* W_ah  = (const float*)d_in[7];
  const float* b_ah  = (const float*)d_in[8];
  const float* W_ap  = (const float*)d_in[9];
  const float* b_ap  = (const float*)d_in[10];
  const float* W_av  = (const float*)d_in[11];
  const float* b_av  = (const float*)d_in[12];
  const float* W_ol  = (const float*)d_in[13];
  const float* b_ol  = (const float*)d_in[14];
  const float* W_oh  = (const float*)d_in[15];
  const float* b_oh  = (const float*)d_in[16];
  const float* W_op  = (const float*)d_in[17];
  const float* b_op  = (const float*)d_in[18];
  const float* W_ov  = (const float*)d_in[19];
  const float* b_ov  = (const float*)d_in[20];
  float* out = (float*)d_out;
  u16* ws = (u16*)d_ws;

  u16* feat = ws + OFF_FEAT;
  u16* wal  = ws + OFF_WAL;
  u16* win  = ws + OFF_WIN;
  u16* wout = ws + OFF_WOUT;
  u16* wah  = ws + OFF_WAH;
  u16* wol  = ws + OFF_WOL;
  u16* woh  = ws + OFF_WOH;
  u16* cat  = ws + OFF_CAT;   // B x 1024 : [agent_latent | attn_out]
  u16* opp  = ws + OFF_OPP;   // B x 1536 : opp_lat, col block o
  u16* qb   = ws + OFF_Q;     // B x 512
  u16* kvb  = ws + OFF_KV;    // 3 x B x 1024 : [k | v]
  u16* att  = ws + OFF_ATT;   // B x 512
  u16* agh  = ws + OFF_AGH;   // B x 512
  u16* oph  = ws + OFF_OPH;   // 3 x B x 512

  convert_all<<<12544, 256, 0, stream>>>(f, W_al, W_in, W_out, W_ah, W_ol, W_oh, ws);

  // agent_latent = elu(feat @ W_al^T + b_al) -> cat[:, :512]
  gemm_bt<64, true><<<dim3(8, 64, 1), 256, 0, stream>>>(
      feat, wal, cat, b_al, 1024, 1024, 1024, 1024, 0, 0, 0, 0, 1.f);
  // opp_lat = elu(feat @ W_ol_stacked^T + b_ol) -> opp (B x 1536)
  gemm_bt<128, true><<<dim3(12, 64, 1), 256, 0, stream>>>(
      feat, wol, opp, b_ol, 1024, 1024, 1024, 1536, 0, 0, 0, 0, 1.f);
  // q = (agent_latent @ Wq^T + bq) / sqrt(128)
  gemm_bt<64, false><<<dim3(8, 64, 1), 256, 0, stream>>>(
      cat, win, qb, b_in, 512, 1024, 512, 512, 0, 0, 0, 0, 0.08838834764831845f);
  // kv[o] = opp_lat[o] @ [Wk;Wv]^T + [bk;bv]   (z = o)
  gemm_bt<128, false><<<dim3(8, 64, 3), 256, 0, stream>>>(
      opp, win + 262144, kvb, b_in + 512, 512, 1536, 512, 1024, 512, 0, 8388608, 0, 1.f);

  attn_kernel<<<2048, 256, 0, stream>>>(qb, kvb, att, out + OUT_IN);

  // attn_out = attn @ W_out^T + b_out -> cat[:, 512:]
  gemm_bt<64, false><<<dim3(8, 64, 1), 256, 0, stream>>>(
      att, wout, cat + 512, b_out, 512, 512, 512, 1024, 0, 0, 0, 0, 1.f);
  // agent_head = elu(cat @ W_ah^T + b_ah)
  gemm_bt<64, true><<<dim3(8, 64, 1), 256, 0, stream>>>(
      cat, wah, agh, b_ah, 1024, 1024, 1024, 512, 0, 0, 0, 0, 1.f);
  // opp_heads[o] = elu(opp_lat[o] @ W_oh[o]^T + b_oh[o])
  gemm_bt<128, true><<<dim3(4, 64, 3), 256, 0, stream>>>(
      opp, woh, oph, b_oh, 512, 1536, 512, 512, 512, 262144, 4194304, 512, 1.f);

  heads_kernel<<<256, 256, 0, stream>>>(agh, oph, W_ap, b_ap, W_av, b_av,
                                        W_op, b_op, W_ov, b_ov, out);
}